// Round 15
// baseline (64.838 us; speedup 1.0000x reference)
//
#include <hip/hip_runtime.h>
#include <hip/hip_bf16.h>

// Problem constants (fixed by the reference)
#define Bz 8
#define Cc 256
#define HWp 23104            // 152*152
#define Kk 1024
#define BK (Bz*Kk)
#define MARGIN_F 10.0f
#define BIGF 1e30f
#define TILE 128
#define NBK 128              // buckets (hw>>8 in [0,90], padded to 128)

typedef __attribute__((ext_vector_type(8))) short bf16x8;  // 8 bf16 = 4 VGPRs
typedef __attribute__((ext_vector_type(4))) float f32x4;   // MFMA 16x16 accumulator

// ---------------------------------------------------------------------------
// K0: per-batch BUCKET sort (verbatim R13, ~1us).  bucket = hw>>8; 3 barriers:
// LDS histogram -> serial 128-prefix -> scatter via LDS cursor atomicAdd.
// Intra-bucket order is timing-dependent but every output byte downstream is
// order-independent (each k writes only its own row; neg is atomicMin).
// Also does neg_min init (ws poisoned once, never re-poisoned).
// ---------------------------------------------------------------------------
__global__ __launch_bounds__(1024) void bucket_sort(
    const int* __restrict__ ind, uint* __restrict__ sorted,
    unsigned* __restrict__ neg)
{
    __shared__ uint cur[NBK];
    const int b = blockIdx.x, tid = threadIdx.x;
    if (tid < NBK) cur[tid] = 0;
    neg[b * Kk + tid] = __float_as_uint(BIGF);
    __syncthreads();
    int hw = ind[b * Kk + tid];
    int bk = hw >> 8;                       // 0..90
    atomicAdd(&cur[bk], 1u);
    __syncthreads();
    if (tid == 0) {                         // exclusive prefix (serial, 128)
        uint acc = 0;
        #pragma unroll
        for (int i = 0; i < NBK; ++i) { uint c = cur[i]; cur[i] = acc; acc += c; }
    }
    __syncthreads();
    uint slot = atomicAdd(&cur[bk], 1u);    // unique slot within bucket
    sorted[b * Kk + slot] = ((uint)hw << 10) | (uint)tid;
}

// ---------------------------------------------------------------------------
// K1: sorted gather + FUSED rownorm.  R13 lesson: ~30us of the total is
// boundaries/short-kernel tails -> fuse stages structurally.  New mapping:
// block = (8 sorted entries x ALL 256 channels, b) = 128x8 = 1024 blocks;
// thread t = (entry t>>5, channel octet t&31).  A full row's 256 channels
// live in one 32-lane half-wave -> after the 8 scattered loads the thread
// rounds to bf16 and the row ssq is 5 shfl_xor away (offsets 1..16 stay
// within the half).  rownorm kernel (+boundary +8MB re-read) disappears at
// zero added cost.  Writes: 32 lanes x 16B = full 512B row, coalesced,
// exactly once.  scl = deterministic function of row bytes -> duplicate
// rows get identical scl -> d2_dup ~ 0 (the loss signal) preserved.
// ---------------------------------------------------------------------------
__global__ __launch_bounds__(256) void sorted_gather_norm(
    const float* __restrict__ x, const uint* __restrict__ sorted,
    __hip_bfloat16* __restrict__ embr, float* __restrict__ scl)
{
    const int g8 = blockIdx.x, b = blockIdx.y;
    const int t = threadIdx.x;
    const int e = t >> 5;                   // sorted entry 0..7
    const int o = t & 31;                   // channel octet 0..31
    uint ent = sorted[b * Kk + g8 * 8 + e];
    int hw = (int)(ent >> 10), k = (int)(ent & 1023u);
    const float* xp = x + (size_t)(b * Cc + o * 8) * HWp + hw;
    float v[8];
    #pragma unroll
    for (int j = 0; j < 8; ++j) v[j] = xp[(size_t)j * HWp];

    ushort ev[8]; float s2 = 0.f;
    #pragma unroll
    for (int j = 0; j < 8; ++j) {
        ev[j] = __hip_bfloat16_raw(__float2bfloat16(v[j])).x;
        float f = __uint_as_float((uint)ev[j] << 16);
        s2 += f * f;
    }
    #pragma unroll
    for (int off = 1; off < 32; off <<= 1) s2 += __shfl_xor(s2, off);

    uint4 oo = make_uint4((uint)ev[0] | ((uint)ev[1] << 16),
                          (uint)ev[2] | ((uint)ev[3] << 16),
                          (uint)ev[4] | ((uint)ev[5] << 16),
                          (uint)ev[6] | ((uint)ev[7] << 16));
    *(uint4*)((ushort*)embr + (size_t)(b * Kk + k) * Cc + o * 8) = oo;
    if (o == 0)
        scl[b * Kk + k] = 10.0f / fmaxf(sqrtf(s2), 1e-12f);
}

// ---------------------------------------------------------------------------
// K2: Gram via bf16 MFMA with LDS-staged panels (verbatim R5/R11, proven) +
// fused masked-min.  d2 = 200 - 2*scl_i*scl_j*Graw, clamped >= 0 BEFORE the
// uint-bit atomicMin (duplicate-index pairs = the loss signal).
// ---------------------------------------------------------------------------
__global__ __launch_bounds__(256) void gram_mfma_min(
    const __hip_bfloat16* __restrict__ emb, const float* __restrict__ scl,
    const int* __restrict__ mask, unsigned* __restrict__ neg)
{
    __shared__ __align__(16) short As[TILE * 64];   // 16 KB
    __shared__ __align__(16) short Bs[TILE * 64];   // 16 KB
    int b  = blockIdx.z;
    int i0 = blockIdx.y * TILE;
    int j0 = blockIdx.x * TILE;
    int w  = threadIdx.x >> 6, l = threadIdx.x & 63;
    int wr = w >> 1, wc = w & 1;          // wave's 64x64 quadrant
    int lr = l & 15, lg = l >> 4;         // lane row / k-group

    const short* E  = (const short*)emb + (size_t)b * Kk * Cc;
    const short* EA = E + (size_t)i0 * Cc;
    const short* EB = E + (size_t)j0 * Cc;

    // staging: instr t (=w*4+q) fills LDS rows t*8..t*8+7; lane l ->
    // row offset l/8, slot l%8; source k-chunk = (l%8) ^ (l/8).
    const int lrow = l >> 3;
    const int lsub = (l & 7) ^ lrow;

    f32x4 acc[4][4] = {};
    for (int k0 = 0; k0 < Cc; k0 += 64) {
        #pragma unroll
        for (int q = 0; q < 4; ++q) {
            int t = w * 4 + q;
            int r = t * 8 + lrow;
            __builtin_amdgcn_global_load_lds(
                (const __attribute__((address_space(1))) void*)(EA + (size_t)r * Cc + k0 + lsub * 8),
                (__attribute__((address_space(3))) void*)&As[t * 512], 16, 0, 0);
            __builtin_amdgcn_global_load_lds(
                (const __attribute__((address_space(1))) void*)(EB + (size_t)r * Cc + k0 + lsub * 8),
                (__attribute__((address_space(3))) void*)&Bs[t * 512], 16, 0, 0);
        }
        __syncthreads();

        #pragma unroll
        for (int kk = 0; kk < 2; ++kk) {
            bf16x8 af[4], bf[4];
            #pragma unroll
            for (int f = 0; f < 4; ++f) {
                int ra = wr * 64 + f * 16 + lr;
                af[f] = *(const bf16x8*)&As[ra * 64 + (((kk * 4 + lg) ^ (ra & 7)) << 3)];
                int rb = wc * 64 + f * 16 + lr;
                bf[f] = *(const bf16x8*)&Bs[rb * 64 + (((kk * 4 + lg) ^ (rb & 7)) << 3)];
            }
            #pragma unroll
            for (int fi = 0; fi < 4; ++fi)
                #pragma unroll
                for (int fj = 0; fj < 4; ++fj)
                    acc[fi][fj] = __builtin_amdgcn_mfma_f32_16x16x32_bf16(
                                      af[fi], bf[fj], acc[fi][fj], 0, 0, 0);
        }
        __syncthreads();
    }

    const int* mb = mask + b * Kk;
    float cjv[4]; int jgv[4]; bool jva[4];
    #pragma unroll
    for (int fj = 0; fj < 4; ++fj) {
        int jg = j0 + wc*64 + fj*16 + lr;
        jgv[fj] = jg;
        cjv[fj] = scl[b * Kk + jg];
        jva[fj] = (mb[jg] != 0);
    }
    #pragma unroll
    for (int fi = 0; fi < 4; ++fi) {
        #pragma unroll
        for (int r = 0; r < 4; ++r) {
            int ig = i0 + wr*64 + fi*16 + 4*lg + r;
            float ci = scl[b * Kk + ig];
            float m = BIGF;
            #pragma unroll
            for (int fj = 0; fj < 4; ++fj) {
                float d2 = fmaxf(200.0f - 2.0f * ci * cjv[fj] * acc[fi][fj][r], 0.0f);
                bool ok = jva[fj] && (jgv[fj] != ig);
                m = ok ? fminf(m, d2) : m;
            }
            #pragma unroll
            for (int off = 1; off < 16; off <<= 1)
                m = fminf(m, __shfl_xor(m, off));
            if (lr == 0)
                atomicMin(&neg[b * Kk + ig], __float_as_uint(m));
        }
    }
}

// ---------------------------------------------------------------------------
// K3: hinge + mean (verbatim R6/R11, proven).
// ---------------------------------------------------------------------------
__global__ __launch_bounds__(1024) void hinge_final(
    const unsigned* __restrict__ neg, const int* __restrict__ mask,
    float* __restrict__ out)
{
    float h = 0.f, v = 0.f;
    for (int i = threadIdx.x; i < BK; i += 1024) {
        if (mask[i] != 0) {
            float d = sqrtf(__uint_as_float(neg[i]));
            h += fmaxf(MARGIN_F - d, 0.f);
            v += 1.f;
        }
    }
    #pragma unroll
    for (int off = 32; off; off >>= 1) {
        h += __shfl_xor(h, off);
        v += __shfl_xor(v, off);
    }
    __shared__ float sh[16], sv[16];
    int w = threadIdx.x >> 6;
    if ((threadIdx.x & 63) == 0) { sh[w] = h; sv[w] = v; }
    __syncthreads();
    if (threadIdx.x == 0) {
        float H = 0.f, V = 0.f;
        #pragma unroll
        for (int i = 0; i < 16; ++i) { H += sh[i]; V += sv[i]; }
        out[0] = H / V;
    }
}

// ---------------------------------------------------------------------------
extern "C" void kernel_launch(void* const* d_in, const int* in_sizes, int n_in,
                              void* d_out, int out_size, void* d_ws, size_t ws_size,
                              hipStream_t stream) {
    const float* x    = (const float*)d_in[0];   // [B,C,H,W] fp32
    const int*   ind  = (const int*)d_in[1];     // [B,K] int32
    const int*   mask = (const int*)d_in[2];     // [B,K] int32
    float* out = (float*)d_out;

    // ws layout: embr bf16 [B*K][C] (4 MB) | scl f32 [B*K] | neg u32 [B*K]
    //            | sorted u32 [B*K]
    __hip_bfloat16* embr = (__hip_bfloat16*)d_ws;
    float*    scl    = (float*)((char*)d_ws + (size_t)BK * Cc * sizeof(__hip_bfloat16));
    unsigned* neg    = (unsigned*)(scl + BK);
    uint*     sorted = (uint*)(neg + BK);

    bucket_sort<<<Bz, 1024, 0, stream>>>(ind, sorted, neg);
    dim3 g1(Kk / 8, Bz);                      // (128 entry-groups, 8 batches)
    sorted_gather_norm<<<g1, 256, 0, stream>>>(x, sorted, embr, scl);
    dim3 g2(Kk / TILE, Kk / TILE, Bz);
    gram_mfma_min<<<g2, 256, 0, stream>>>(embr, scl, mask, neg);
    hinge_final<<<1, 1024, 0, stream>>>(neg, mask, out);
}